// Round 11
// baseline (773.085 us; speedup 1.0000x reference)
//
#include <hip/hip_runtime.h>
#include <hip/hip_cooperative_groups.h>

namespace cg = cooperative_groups;

#define N_USERC 50000
#define N_ITEMC 100000
#define NN      150000      // total nodes
#define DD      64
#define NLAYER  3
#define NNZC    2400000
#define BB      4096
#define NRID    (3*BB)      // 12288 gathered output rows
#define NBKT    147         // ceil(NN/1024) row buckets (row>>10)
#define NABLK   586         // ceil(NNZC/4096) partition blocks
#define NTILE   4688        // ceil(NN/32) 32-row tiles (fused layer kernel)
#define ELLW    32          // ELL width: P(deg>32 | Poisson(16)) ~ 1.4e-4
#define ELLROWS 150528      // NBKT*1024 (phaseB covers padded row space)
#define OVCAP   32768       // overflow COO capacity (expected ~40 entries)
#define NWPB    97          // wprep vblocks
#define NIB     9375        // Eb0-init vblocks (NN*DD/4 / 256)
#define NOSB    3072        // slice0 / outnorm vblocks (NRID/4)
#define NV1     (NWPB + NABLK + NIB + NOSB)   // stage-1 vblock count
#define CGRID   768         // coop grid: 3 blocks/CU — co-residency guaranteed

typedef unsigned short ushort_t;
typedef __attribute__((ext_vector_type(8))) short bf16x8;   // 8 bf16 = 4 VGPRs (A/B frag)
typedef __attribute__((ext_vector_type(4))) float f32x4;    // C/D frag

static __device__ __forceinline__ float bf2f(ushort_t b) {
    unsigned int u = ((unsigned int)b) << 16;
    return __uint_as_float(u);
}
static __device__ __forceinline__ ushort_t f2bf(float f) {
    unsigned int u = __float_as_uint(f);
    u = u + 0x7FFFu + ((u >> 16) & 1u);   // round-to-nearest-even
    return (ushort_t)(u >> 16);
}

// ======================= stage bodies (shared by coop kernel + fallback) ====

// block-0 stage: dtype sniff + zero bucket counters + ovcnt
static __device__ void d_sniff0(const unsigned int* ue_words, int* flag,
                                int* bucket_cnt, int* ovcnt) {
    int t = threadIdx.x;
    if (t < 64) {
        int cnt = 0;
        for (int i = 0; i < 4; i++) {
            unsigned int w = ue_words[t * 4 + i];
            unsigned int lo = w & 0xFFFFu;
            unsigned int ex = (lo >> 7) & 0xFF;
            if (ex >= 100 && ex <= 132) cnt++;
        }
        for (int m = 1; m < 64; m <<= 1) cnt += __shfl_xor(cnt, m, 64);
        if (t == 0) *flag = (cnt >= 128) ? 1 : 0;
    } else if (t - 64 < NBKT) {
        bucket_cnt[t - 64] = 0;
    } else if (t == 255) {
        *ovcnt = 0;
    }
}

// W-frag pack + bias sums. Wfrag layout: [l][s(4)][jt(4)][lane(64)][i(8)].
// B-frag (16x16x32): col = jt*16 + (lane&15); k = 32*(s&1) + 8*(lane>>4) + i;
// matrix = W1 for s<2, W2 for s>=2. A-side uses the identical k map, so any
// HW k-permutation cancels.
static __device__ void d_wprep(int vb, int isbf,
                               const void* W1, const void* W2,
                               const void* b1, const void* b2,
                               ushort_t* Wfrag, float* bsum) {
    int idx = vb * 256 + threadIdx.x;
    if (idx < NLAYER * 4 * 4 * 64 * 8) {
        int i    = idx & 7;
        int lane = (idx >> 3) & 63;
        int jt   = (idx >> 9) & 3;
        int s    = (idx >> 11) & 3;
        int l    = idx >> 13;
        int kfull = 32 * (s & 1) + 8 * (lane >> 4) + i;
        int col   = jt * 16 + (lane & 15);
        const void* W = (s < 2) ? W1 : W2;
        size_t off = (size_t)l * 4096 + (size_t)kfull * 64 + col;
        float v = isbf ? bf2f(((const ushort_t*)W)[off]) : ((const float*)W)[off];
        Wfrag[idx] = f2bf(v);
    } else {
        int r = idx - NLAYER * 4 * 4 * 64 * 8;
        if (r < NLAYER * 64) {
            float v1 = isbf ? bf2f(((const ushort_t*)b1)[r]) : ((const float*)b1)[r];
            float v2 = isbf ? bf2f(((const ushort_t*)b2)[r]) : ((const float*)b2)[r];
            bsum[r] = v1 + v2;
        }
    }
}

// bucket histogram chunk (4096 edges)
static __device__ void d_hist(int vb, const int* rows, int* bucket_cnt, int* sh) {
    int t = threadIdx.x;
    if (t < NBKT) sh[t] = 0;
    __syncthreads();
    int e0 = vb * 4096;
#pragma unroll
    for (int i = 0; i < 16; i++) {
        int e = e0 + t + i * 256;
        if (e < NNZC) atomicAdd(&sh[rows[e] >> 10], 1);
    }
    __syncthreads();
    if (t < NBKT && sh[t]) atomicAdd(&bucket_cnt[t], sh[t]);
    __syncthreads();
}

// Eb0 bf16 init chunk (bf16 inputs: lossless bit copy; fp32: round)
static __device__ void d_init(int vb, int isbf, const void* ue, const void* ie,
                              ushort_t* Eb0) {
    int i4 = vb * 256 + threadIdx.x;            // over NN*DD/4
    if (i4 < NN * DD / 4) {
        int idx = i4 * 4;
        int row = idx >> 6;
        bool isU = row < N_USERC;
        int si = isU ? idx : idx - N_USERC * DD;
        if (isbf) {
            const uint2* src = (const uint2*)((const ushort_t*)(isU ? ue : ie) + si);
            *(uint2*)(Eb0 + idx) = *src;
        } else {
            const float* src = (const float*)(isU ? ue : ie) + si;
            ushort_t o[4];
#pragma unroll
            for (int k = 0; k < 4; k++) o[k] = f2bf(src[k]);
            *(uint2*)(Eb0 + idx) = *(uint2*)o;
        }
    }
}

static __device__ __forceinline__ int rid_to_node(int rid,
                                                  const int* users, const int* pos, const int* neg) {
    if (rid < BB)      return users[rid] - 1;
    if (rid < 2 * BB)  return N_USERC + pos[rid - BB] - 1;
    return N_USERC + neg[rid - 2 * BB] - 1;
}

// output slice 0 chunk: raw initial embedding read directly from inputs
static __device__ void d_slice0(int vb, int isbf, const void* ue, const void* ie,
                                const int* users, const int* pos, const int* neg,
                                float* out) {
    int rid  = vb * 4 + (threadIdx.x >> 6);
    int lane = threadIdx.x & 63;
    if (rid < NRID) {
        int node = rid_to_node(rid, users, pos, neg);
        bool isU = node < N_USERC;
        int si = (isU ? node : node - N_USERC) * DD + lane;
        float v = isbf ? bf2f(isU ? ((const ushort_t*)ue)[si] : ((const ushort_t*)ie)[si])
                       : (isU ? ((const float*)ue)[si] : ((const float*)ie)[si]);
        out[(size_t)rid * 256 + lane] = v;
    }
}

// exclusive scan of 147 bucket counts (single block)
static __device__ void d_bscan(const int* bucket_cnt, int* gbase, int* gcursor,
                               int* sh) {
    int t = threadIdx.x;
    int v = (t < NBKT) ? bucket_cnt[t] : 0;
    sh[t] = v; __syncthreads();
    for (int off = 1; off < 256; off <<= 1) {
        int x = (t >= off) ? sh[t - off] : 0;
        __syncthreads();
        sh[t] += x;
        __syncthreads();
    }
    if (t < NBKT) { int ex = sh[t] - v; gbase[t] = ex; gcursor[t] = ex; }
    if (t == 0) { gbase[NBKT] = NNZC; }
    __syncthreads();
}

// phase A chunk: partition 4096 edges into row-buckets
static __device__ void d_phaseA(int vb, int isbf,
                                const int* rows, const int* cols, const void* vals,
                                int* gcursor, int2* binned,
                                int* shh, int* shb, int* shl) {
    int t = threadIdx.x;
    int e0 = vb * 4096;
    if (t < NBKT) { shh[t] = 0; shl[t] = 0; }
    __syncthreads();
    int myrow[16];
#pragma unroll
    for (int i = 0; i < 16; i++) {
        int e = e0 + t + i * 256;
        int r = -1;
        if (e < NNZC) { r = rows[e]; atomicAdd(&shh[r >> 10], 1); }
        myrow[i] = r;
    }
    __syncthreads();
    if (t < NBKT && shh[t] > 0) shb[t] = atomicAdd(&gcursor[t], shh[t]);
    __syncthreads();
#pragma unroll
    for (int i = 0; i < 16; i++) {
        int e = e0 + t + i * 256;
        if (e < NNZC) {
            int r = myrow[i];
            int bkt = r >> 10;
            int off = atomicAdd(&shl[bkt], 1);
            int pos = shb[bkt] + off;
            int c = cols[e];
            float v = isbf ? bf2f(((const ushort_t*)vals)[e]) : ((const float*)vals)[e];
            binned[pos] = make_int2(((r & 1023) << 18) | c, __float_as_int(v));
        }
    }
    __syncthreads();
}

// phase B bucket: scatter edges into ELL (bucket-local 256KB window -> L2-
// resident writes; round-8 lesson: global scatter = 148MB write-allocate).
// Then zero-fill dummy tails only.
static __device__ void d_phaseB(int b, const int* gbase, const int2* binned,
                                int2* ell, int4* ovbuf, int* ovcnt, int* rcur) {
    int t = threadIdx.x;
    int s = gbase[b], e = gbase[b + 1];
    for (int i = t; i < 1024; i += 256) rcur[i] = 0;
    __syncthreads();
    for (int i = s + t; i < e; i += 256) {
        int2 en = binned[i];
        int rl = en.x >> 18;
        int c  = en.x & 0x3FFFF;
        int off = atomicAdd(&rcur[rl], 1);
        if (off < ELLW) {
            ell[((size_t)(b * 1024 + rl)) * ELLW + off] = make_int2(c, en.y);
        } else {
            int p = atomicAdd(ovcnt, 1);
            if (p < OVCAP) ovbuf[p] = make_int4(b * 1024 + rl, c, en.y, 0);
        }
    }
    __syncthreads();
    for (int i = t; i < 1024; i += 256) {
        int start = rcur[i]; if (start > ELLW) start = ELLW;
        int2* rp = ell + ((size_t)(b * 1024 + i)) * ELLW;
        for (int j = start; j < ELLW; j++) rp[j] = make_int2(0, 0);
    }
    __syncthreads();
}

// ================= cooperative build kernel: 6 prep kernels -> 1 launch ====
__global__ __launch_bounds__(256) void k_build(const unsigned int* ue_words,
                                               const void* ue, const void* ie,
                                               const void* W1, const void* W2,
                                               const void* b1, const void* b2,
                                               const int* rows, const int* cols,
                                               const void* vals,
                                               const int* users, const int* pos,
                                               const int* neg,
                                               int* flag, int* bucket_cnt,
                                               int* ovcnt, int* gbase, int* gcursor,
                                               ushort_t* Wfrag, float* bsum,
                                               int2* binned, int2* ell,
                                               int4* ovbuf, ushort_t* Eb0,
                                               float* out) {
    __shared__ int shA[1024];                 // hist / bscan / phaseB cursor
    __shared__ int shB[NBKT], shC[NBKT], shD[NBKT];  // phaseA
    cg::grid_group g = cg::this_grid();

    // stage 0: block 0 sniffs dtype + zeroes counters
    if (blockIdx.x == 0) d_sniff0(ue_words, flag, bucket_cnt, ovcnt);
    g.sync();
    int isbf = *flag;

    // stage 1 (independent, grid-strided): wprep | hist | Eb0-init | slice0
    for (int vb = blockIdx.x; vb < NV1; vb += CGRID) {
        if (vb < NWPB) {
            d_wprep(vb, isbf, W1, W2, b1, b2, Wfrag, bsum);
        } else if (vb < NWPB + NABLK) {
            d_hist(vb - NWPB, rows, bucket_cnt, shA);
        } else if (vb < NWPB + NABLK + NIB) {
            d_init(vb - NWPB - NABLK, isbf, ue, ie, Eb0);
        } else {
            d_slice0(vb - NWPB - NABLK - NIB, isbf, ue, ie, users, pos, neg, out);
        }
    }
    g.sync();

    // stage 2: block 0 scans bucket counts
    if (blockIdx.x == 0) d_bscan(bucket_cnt, gbase, gcursor, shA);
    g.sync();

    // stage 3: phase A partition
    for (int vb = blockIdx.x; vb < NABLK; vb += CGRID)
        d_phaseA(vb, isbf, rows, cols, vals, gcursor, binned, shB, shC, shD);
    g.sync();

    // stage 4: phase B ELL scatter
    for (int vb = blockIdx.x; vb < NBKT; vb += CGRID)
        d_phaseB(vb, gbase, binned, ell, ovbuf, ovcnt, shA);
}

// ===================== fallback (non-cooperative) prep kernels =============
__global__ __launch_bounds__(256) void k_sniffzb(const unsigned int* __restrict__ ue_words,
                                                 int* __restrict__ flag,
                                                 int* __restrict__ bucket_cnt,
                                                 int* __restrict__ ovcnt) {
    d_sniff0(ue_words, flag, bucket_cnt, ovcnt);
}

__global__ __launch_bounds__(256) void k_prep(const void* W1, const void* W2,
                                              const void* b1, const void* b2,
                                              const int* rows, const int* flag,
                                              ushort_t* Wfrag, float* bsum,
                                              int* bucket_cnt) {
    __shared__ int sh[NBKT];
    int isbf = *flag;
    if (blockIdx.x < NWPB) d_wprep(blockIdx.x, isbf, W1, W2, b1, b2, Wfrag, bsum);
    else                   d_hist(blockIdx.x - NWPB, rows, bucket_cnt, sh);
}

__global__ __launch_bounds__(256) void k_bscan(const int* bucket_cnt,
                                               int* gbase, int* gcursor) {
    __shared__ int sh[256];
    d_bscan(bucket_cnt, gbase, gcursor, sh);
}

__global__ __launch_bounds__(256) void k_phaseA(const int* rows, const int* cols,
                                                const void* vals, const int* flag,
                                                int* gcursor, int2* binned) {
    __shared__ int shh[NBKT], shb[NBKT], shl[NBKT];
    d_phaseA(blockIdx.x, *flag, rows, cols, vals, gcursor, binned, shh, shb, shl);
}

__global__ __launch_bounds__(256) void k_phaseB(const int* gbase, const int2* binned,
                                                int2* ell, int4* ovbuf, int* ovcnt) {
    __shared__ int rcur[1024];
    d_phaseB(blockIdx.x, gbase, binned, ell, ovbuf, ovcnt, rcur);
}

__global__ __launch_bounds__(256) void k_initslice(const void* ue, const void* ie,
                                                   const int* flag, ushort_t* Eb0,
                                                   const int* users, const int* pos,
                                                   const int* neg, float* out) {
    int isbf = *flag;
    if (blockIdx.x < NIB) d_init(blockIdx.x, isbf, ue, ie, Eb0);
    else                  d_slice0(blockIdx.x - NIB, isbf, ue, ie, users, pos, neg, out);
}

// ---- fused layer v6 (ELL + 1-row-ahead pipeline + bf16-only state + fused
// prev-layer outnorm): blocks >= NTILE (launched only for layer>=1) compute
// the normalized output slice of the PREVIOUS layer from Eb_in (= prev ebo,
// complete at kernel entry) -> kills 2 outnorm launches and hides the work
// inside this latency-bound kernel. Blocks < NTILE unchanged from v5. ----
__global__ __launch_bounds__(256) void k_layer(const int2* __restrict__ ell,
                                               const int4* __restrict__ ovbuf,
                                               const int* __restrict__ ovcnt,
                                               const ushort_t* __restrict__ Eb_in,
                                               ushort_t* __restrict__ Eb_out,
                                               const ushort_t* __restrict__ Wfrag,
                                               const float* __restrict__ bsum,
                                               const int* __restrict__ users,
                                               const int* __restrict__ pos,
                                               const int* __restrict__ neg,
                                               float* __restrict__ out,
                                               int layer) {
    __shared__ float sLE[32][68];
    __shared__ float sE [32][68];

    int t    = threadIdx.x;
    int lane = t & 63;

    if (blockIdx.x >= NTILE) {
        // outnorm of previous layer's output (Eb_in), cbase = 64*layer
        int rid = (blockIdx.x - NTILE) * 4 + (t >> 6);
        if (rid < NRID) {
            int node = rid_to_node(rid, users, pos, neg);
            float v = bf2f(Eb_in[(size_t)node * DD + lane]);
            float p2 = v * v;
            for (int m = 1; m < 64; m <<= 1) p2 += __shfl_xor(p2, m, 64);
            float nr = fmaxf(sqrtf(p2), 1e-12f);
            out[(size_t)rid * 256 + 64 * layer + lane] = v / nr;
        }
        return;
    }

    int wv   = t >> 6;
    int oct  = lane >> 3;
    int d8   = (lane & 7) * 8;
    int hl   = lane >> 4;
    int l16  = lane & 15;
    int r0   = blockIdx.x << 5;

    // ---- sE staging: issue bf16 row loads now; LDS write deferred ----
    int lr_ = t >> 3;
    int dm_ = (t & 7) * 8;
    uint4 ev = make_uint4(0u, 0u, 0u, 0u);
    {
        int gr = r0 + lr_;
        if (gr < NN) ev = *(const uint4*)(Eb_in + (size_t)gr * DD + dm_);
    }

    // ---- phase 1: ELL spmm, 8 rows/wave, gather 1-row-ahead ----
    int baseRow = r0 + wv * 8;                       // max 150015 < ELLROWS
    int2 pv_c[4], pv_n[4];
    uint4 q_c[4];
#pragma unroll
    for (int v = 0; v < 4; v++)
        pv_c[v] = ell[(size_t)baseRow * ELLW + v * 8 + oct];
#pragma unroll
    for (int v = 0; v < 4; v++)
        q_c[v] = *(const uint4*)(Eb_in + ((size_t)(unsigned)pv_c[v].x << 6) + d8);
#pragma unroll
    for (int v = 0; v < 4; v++)
        pv_n[v] = ell[(size_t)(baseRow + 1) * ELLW + v * 8 + oct];

#pragma unroll
    for (int sub = 0; sub < 8; sub++) {
        uint4 q_n[4];
        int2 pv_n2[4];
        if (sub < 7) {
#pragma unroll
            for (int v = 0; v < 4; v++)
                q_n[v] = *(const uint4*)(Eb_in + ((size_t)(unsigned)pv_n[v].x << 6) + d8);
        }
        if (sub < 6) {
#pragma unroll
            for (int v = 0; v < 4; v++)
                pv_n2[v] = ell[(size_t)(baseRow + sub + 2) * ELLW + v * 8 + oct];
        }
        float acc[8];
#pragma unroll
        for (int k = 0; k < 8; k++) acc[k] = 0.f;
#pragma unroll
        for (int v = 0; v < 4; v++) {
            float w = __int_as_float(pv_c[v].y);
            acc[0] = fmaf(w, __uint_as_float(q_c[v].x << 16),         acc[0]);
            acc[1] = fmaf(w, __uint_as_float(q_c[v].x & 0xffff0000u), acc[1]);
            acc[2] = fmaf(w, __uint_as_float(q_c[v].y << 16),         acc[2]);
            acc[3] = fmaf(w, __uint_as_float(q_c[v].y & 0xffff0000u), acc[3]);
            acc[4] = fmaf(w, __uint_as_float(q_c[v].z << 16),         acc[4]);
            acc[5] = fmaf(w, __uint_as_float(q_c[v].z & 0xffff0000u), acc[5]);
            acc[6] = fmaf(w, __uint_as_float(q_c[v].w << 16),         acc[6]);
            acc[7] = fmaf(w, __uint_as_float(q_c[v].w & 0xffff0000u), acc[7]);
        }
#pragma unroll
        for (int m = 8; m < 64; m <<= 1)
#pragma unroll
            for (int k = 0; k < 8; k++) acc[k] += __shfl_xor(acc[k], m, 64);
        if (oct == 0) {
            int lr = wv * 8 + sub;
            *(float4*)&sLE[lr][d8]     = make_float4(acc[0], acc[1], acc[2], acc[3]);
            *(float4*)&sLE[lr][d8 + 4] = make_float4(acc[4], acc[5], acc[6], acc[7]);
        }
#pragma unroll
        for (int v = 0; v < 4; v++) {
            pv_c[v] = pv_n[v];
            q_c[v]  = q_n[v];
            pv_n[v] = pv_n2[v];
        }
    }

    // sE LDS write: unpack 8 bf16 -> f32 (loads landed long ago)
    sE[lr_][dm_ + 0] = __uint_as_float(ev.x << 16);
    sE[lr_][dm_ + 1] = __uint_as_float(ev.x & 0xffff0000u);
    sE[lr_][dm_ + 2] = __uint_as_float(ev.y << 16);
    sE[lr_][dm_ + 3] = __uint_as_float(ev.y & 0xffff0000u);
    sE[lr_][dm_ + 4] = __uint_as_float(ev.z << 16);
    sE[lr_][dm_ + 5] = __uint_as_float(ev.z & 0xffff0000u);
    sE[lr_][dm_ + 6] = __uint_as_float(ev.w << 16);
    sE[lr_][dm_ + 7] = __uint_as_float(ev.w & 0xffff0000u);
    __syncthreads();

    // ---- overflow COO: wave 0 scans the tiny list (expected ~40 entries) ----
    {
        int n = *ovcnt;
        n = (n < OVCAP) ? n : OVCAP;
        if (wv == 0) {
            for (int i = 0; i < n; i++) {
                int4 ov = ovbuf[i];
                if ((unsigned)(ov.x - r0) < 32u) {
                    float w = __int_as_float(ov.z);
                    sLE[ov.x - r0][lane] += w * bf2f(Eb_in[(size_t)ov.y * DD + lane]);
                }
            }
        }
    }
    __syncthreads();

    // ---- phase 2: dense MFMA. wave -> (rt = wv&1, jts = pair wv>>1) ----
    int rt = wv & 1;
    int j0w = wv >> 1;
    int jtA = 2 * j0w, jtB = 2 * j0w + 1;
    const uint4* wb = (const uint4*)(Wfrag + (size_t)layer * 8192);
    float bsA = bsum[layer * 64 + jtA * 16 + l16];
    float bsB = bsum[layer * 64 + jtB * 16 + l16];

    f32x4 accA = (f32x4){0.f, 0.f, 0.f, 0.f};
    f32x4 accB = (f32x4){0.f, 0.f, 0.f, 0.f};
    int lrow = rt * 16 + l16;

#pragma unroll
    for (int sh = 0; sh < 2; sh++) {
        bf16x8 w1a, w1b, w2a, w2b;
        {
            uint4 qa = wb[(sh * 4 + jtA) * 64 + lane];
            uint4 qb = wb[(sh * 4 + jtB) * 64 + lane];
            uint4 qc = wb[((2 + sh) * 4 + jtA) * 64 + lane];
            uint4 qd = wb[((2 + sh) * 4 + jtB) * 64 + lane];
            __builtin_memcpy(&w1a, &qa, 16);
            __builtin_memcpy(&w1b, &qb, 16);
            __builtin_memcpy(&w2a, &qc, 16);
            __builtin_memcpy(&w2b, &qd, 16);
        }
        const float* pl = &sLE[lrow][sh * 32 + hl * 8];
        const float* pe = &sE [lrow][sh * 32 + hl * 8];
        float4 l0 = *(const float4*)pl, l1 = *(const float4*)(pl + 4);
        float4 e0 = *(const float4*)pe, e1 = *(const float4*)(pe + 4);
        float le[8] = {l0.x, l0.y, l0.z, l0.w, l1.x, l1.y, l1.z, l1.w};
        float ee[8] = {e0.x, e0.y, e0.z, e0.w, e1.x, e1.y, e1.z, e1.w};
        unsigned int u1h[4], u1l[4], u2h[4], u2l[4];
#pragma unroll
        for (int d = 0; d < 4; d++) {
            float s0 = le[2*d]   + ee[2*d];
            float s1 = le[2*d+1] + ee[2*d+1];
            float m0 = le[2*d]   * ee[2*d];
            float m1 = le[2*d+1] * ee[2*d+1];
            asm("v_cvt_pk_bf16_f32 %0, %1, %2" : "=v"(u1h[d]) : "v"(s0), "v"(s1));
            asm("v_cvt_pk_bf16_f32 %0, %1, %2" : "=v"(u2h[d]) : "v"(m0), "v"(m1));
            float s0r = s0 - __uint_as_float(u1h[d] << 16);
            float s1r = s1 - __uint_as_float(u1h[d] & 0xffff0000u);
            float m0r = m0 - __uint_as_float(u2h[d] << 16);
            float m1r = m1 - __uint_as_float(u2h[d] & 0xffff0000u);
            asm("v_cvt_pk_bf16_f32 %0, %1, %2" : "=v"(u1l[d]) : "v"(s0r), "v"(s1r));
            asm("v_cvt_pk_bf16_f32 %0, %1, %2" : "=v"(u2l[d]) : "v"(m0r), "v"(m1r));
        }
        bf16x8 p1h, p1l, p2h, p2l;
        __builtin_memcpy(&p1h, u1h, 16);
        __builtin_memcpy(&p1l, u1l, 16);
        __builtin_memcpy(&p2h, u2h, 16);
        __builtin_memcpy(&p2l, u2l, 16);

        accA = __builtin_amdgcn_mfma_f32_16x16x32_bf16(p1h, w1a, accA, 0, 0, 0);
        accA = __builtin_amdgcn_mfma_f32_16x16x32_bf16(p1l, w1a, accA, 0, 0, 0);
        accA = __builtin_amdgcn_mfma_f32_16x16x32_bf16(p2h, w2a, accA, 0, 0, 0);
        accA = __builtin_amdgcn_mfma_f32_16x16x32_bf16(p2l, w2a, accA, 0, 0, 0);
        accB = __builtin_amdgcn_mfma_f32_16x16x32_bf16(p1h, w1b, accB, 0, 0, 0);
        accB = __builtin_amdgcn_mfma_f32_16x16x32_bf16(p1l, w1b, accB, 0, 0, 0);
        accB = __builtin_amdgcn_mfma_f32_16x16x32_bf16(p2h, w2b, accB, 0, 0, 0);
        accB = __builtin_amdgcn_mfma_f32_16x16x32_bf16(p2l, w2b, accB, 0, 0, 0);
    }

    // epilogue: bias + leaky relu -> Eb_out only (bf16 state)
#pragma unroll
    for (int g = 0; g < 4; g++) {
        int r = r0 + rt * 16 + hl * 4 + g;
        if (r < NN) {
            float hA = accA[g] + bsA; hA = (hA >= 0.f) ? hA : 0.2f * hA;
            float hB = accB[g] + bsB; hB = (hB >= 0.f) ? hB : 0.2f * hB;
            Eb_out[(size_t)r * DD + jtA * 16 + l16] = f2bf(hA);
            Eb_out[(size_t)r * DD + jtB * 16 + l16] = f2bf(hB);
        }
    }
}

// ---- final outnorm (layer NLAYER-1 output; earlier ones fused in k_layer) ----
__global__ __launch_bounds__(256) void k_outnorm(const ushort_t* __restrict__ Eb,
                                                 const int* __restrict__ users,
                                                 const int* __restrict__ pos,
                                                 const int* __restrict__ neg,
                                                 float* __restrict__ out,
                                                 int cbase) {
    int rid  = blockIdx.x * 4 + (threadIdx.x >> 6);
    int lane = threadIdx.x & 63;
    if (rid >= NRID) return;
    int node = rid_to_node(rid, users, pos, neg);
    float v = bf2f(Eb[(size_t)node * DD + lane]);
    float p2 = v * v;
    for (int m = 1; m < 64; m <<= 1) p2 += __shfl_xor(p2, m, 64);
    float nr = fmaxf(sqrtf(p2), 1e-12f);
    out[(size_t)rid * 256 + cbase + lane] = v / nr;
}

extern "C" void kernel_launch(void* const* d_in, const int* in_sizes, int n_in,
                              void* d_out, int out_size, void* d_ws, size_t ws_size,
                              hipStream_t stream) {
    const void* ue   = d_in[0];
    const void* ie   = d_in[1];
    const void* ev   = d_in[2];
    const void* W1   = d_in[3];
    const void* b1   = d_in[4];
    const void* W2   = d_in[5];
    const void* b2   = d_in[6];
    const int*  ei   = (const int*)d_in[7];
    const int*  usr  = (const int*)d_in[8];
    const int*  posi = (const int*)d_in[9];
    const int*  negi = (const int*)d_in[10];
    float*      out  = (float*)d_out;

    const int* rows = ei;
    const int* cols = ei + NNZC;

    // workspace carve — ~97 MB (Eb0 no longer aliases binned: in the coop
    // kernel Eb0-init runs BEFORE phaseA writes binned)
    char* w = (char*)d_ws;
    ushort_t* Eb1     = (ushort_t*)w; w += (size_t)NN * DD * 2;      // 19.20 MB
    ushort_t* Eb0     = (ushort_t*)w; w += (size_t)NN * DD * 2;      // 19.20 MB
    int2*   binned    = (int2*)w;   w += (size_t)NNZC * 8;           // 19.20 MB
    int2*   ell       = (int2*)w;   w += (size_t)ELLROWS * ELLW * 8; // 38.54 MB
    int4*   ovbuf     = (int4*)w;   w += (size_t)OVCAP * 16;         // 0.52 MB
    int*    ovcnt     = (int*)w;    w += 256;
    int*    gbase     = (int*)w;    w += 1024;
    int*    gcursor   = (int*)w;    w += 1024;
    int*    bucket_cnt= (int*)w;    w += 1024;
    int*    flag      = (int*)w;    w += 256;
    ushort_t* Wfrag   = (ushort_t*)w; w += 49152;                    // 3*4*4*64*8 bf16
    float*  bsum      = (float*)w;  w += 768;                        // 3*64 fp32

    const unsigned int* ue_words = (const unsigned int*)ue;

    // single cooperative build kernel (sniff+wprep+hist+init+slice0+scan+
    // phaseA+phaseB); fallback to discrete kernels if coop launch fails
    void* args[] = {
        (void*)&ue_words, (void*)&ue, (void*)&ie,
        (void*)&W1, (void*)&W2, (void*)&b1, (void*)&b2,
        (void*)&rows, (void*)&cols, (void*)&ev,
        (void*)&usr, (void*)&posi, (void*)&negi,
        (void*)&flag, (void*)&bucket_cnt, (void*)&ovcnt,
        (void*)&gbase, (void*)&gcursor,
        (void*)&Wfrag, (void*)&bsum,
        (void*)&binned, (void*)&ell, (void*)&ovbuf,
        (void*)&Eb0, (void*)&out
    };
    hipError_t cerr = hipLaunchCooperativeKernel((const void*)k_build,
                                                 dim3(CGRID), dim3(256),
                                                 args, 0, stream);
    if (cerr != hipSuccess) {
        k_sniffzb<<<1, 256, 0, stream>>>(ue_words, flag, bucket_cnt, ovcnt);
        k_prep<<<NWPB + NABLK, 256, 0, stream>>>(W1, W2, b1, b2, rows, flag,
                                                 Wfrag, bsum, bucket_cnt);
        k_bscan<<<1, 256, 0, stream>>>(bucket_cnt, gbase, gcursor);
        k_phaseA<<<NABLK, 256, 0, stream>>>(rows, cols, ev, flag, gcursor, binned);
        k_phaseB<<<NBKT, 256, 0, stream>>>(gbase, binned, ell, ovbuf, ovcnt);
        k_initslice<<<NIB + NOSB, 256, 0, stream>>>(ue, ie, flag, Eb0,
                                                    usr, posi, negi, out);
    }

    for (int l = 0; l < NLAYER; l++) {
        const ushort_t* ebi = (l & 1) ? Eb1 : Eb0;
        ushort_t*       ebo = (l & 1) ? Eb0 : Eb1;
        int grid = (l == 0) ? NTILE : (NTILE + NOSB);   // l>=1: + fused outnorm(l-1)
        k_layer<<<grid, 256, 0, stream>>>(ell, ovbuf, ovcnt, ebi, ebo, Wfrag, bsum,
                                          usr, posi, negi, out, l);
    }
    k_outnorm<<<3072, 256, 0, stream>>>(Eb1, usr, posi, negi, out, 64 * NLAYER);
}

// Round 12
// 416.522 us; speedup vs baseline: 1.8560x; 1.8560x over previous
//
#include <hip/hip_runtime.h>

#define N_USERC 50000
#define N_ITEMC 100000
#define NN      150000      // total nodes
#define DD      64
#define NLAYER  3
#define NNZC    2400000
#define BB      4096
#define NRID    (3*BB)      // 12288 gathered output rows
#define NBKT    147         // ceil(NN/1024) row buckets (row>>10)
#define NABLK   586         // ceil(NNZC/4096) partition blocks
#define NTILE   4688        // ceil(NN/32) 32-row tiles (fused layer kernel)
#define ELLW    32          // ELL width: P(deg>32 | Poisson(16)) ~ 1.4e-4
#define ELLROWS 150528      // NBKT*1024 (phaseB covers padded row space)
#define OVCAP   32768       // overflow COO capacity (expected ~40 entries)
#define NWPB    97          // wprep block count
#define NPREPB  (NWPB + NABLK)
#define NIB     9375        // init blocks (NN*DD/4 / 256)
#define NOSB    3072        // outslice0 / outnorm blocks (NRID/4)
#define NISB    (NIB + NOSB)

typedef unsigned short ushort_t;
typedef __attribute__((ext_vector_type(8))) short bf16x8;   // 8 bf16 = 4 VGPRs (A/B frag)
typedef __attribute__((ext_vector_type(4))) float f32x4;    // C/D frag

static __device__ __forceinline__ float bf2f(ushort_t b) {
    unsigned int u = ((unsigned int)b) << 16;
    return __uint_as_float(u);
}
static __device__ __forceinline__ ushort_t f2bf(float f) {
    unsigned int u = __float_as_uint(f);
    u = u + 0x7FFFu + ((u >> 16) & 1u);   // round-to-nearest-even
    return (ushort_t)(u >> 16);
}

// ---- dtype sniff (flag=1 if packed bf16) + zero bucket counters + ovcnt ----
// (round-10 lesson: cooperative grid.sync() on 8 XCDs costs ~100µs/sync via
// cross-XCD coherence flushes — discrete kernels ARE the fast path here.)
__global__ __launch_bounds__(256) void k_sniffzb(const unsigned int* __restrict__ ue_words,
                                                 int* __restrict__ flag,
                                                 int* __restrict__ bucket_cnt,
                                                 int* __restrict__ ovcnt) {
    int t = threadIdx.x;
    if (t < 64) {
        int cnt = 0;
        for (int i = 0; i < 4; i++) {
            unsigned int w = ue_words[t * 4 + i];
            unsigned int lo = w & 0xFFFFu;
            unsigned int ex = (lo >> 7) & 0xFF;
            if (ex >= 100 && ex <= 132) cnt++;
        }
        for (int m = 1; m < 64; m <<= 1) cnt += __shfl_xor(cnt, m, 64);
        if (t == 0) *flag = (cnt >= 128) ? 1 : 0;
    } else if (t - 64 < NBKT) {
        bucket_cnt[t - 64] = 0;
    } else if (t == 255) {
        *ovcnt = 0;
    }
}

// ---- k_prep: blocks [0,NWPB) = W-frag pack + bias sums; blocks [NWPB,..) =
// bucket histogram. (round-8 lesson: DIRECT ELL build = 148MB write-allocate;
// two-phase bucket binning keeps the final scatter L2-local and stays.) ----
// Wfrag layout: [l][s(4)][jt(4)][lane(64)][i(8)] ushort.
// B-frag (16x16x32): col = jt*16 + (lane&15); k = 32*(s&1) + 8*(lane>>4) + i;
// matrix = W1 for s<2, W2 for s>=2. A-side uses the identical k map, so any
// HW k-permutation cancels (same map both operands).
__global__ __launch_bounds__(256) void k_prep(const void* __restrict__ W1,
                                              const void* __restrict__ W2,
                                              const void* __restrict__ b1,
                                              const void* __restrict__ b2,
                                              const int* __restrict__ rows,
                                              const int* __restrict__ flag,
                                              ushort_t* __restrict__ Wfrag,
                                              float* __restrict__ bsum,
                                              int* __restrict__ bucket_cnt) {
    __shared__ int h[NBKT];
    if (blockIdx.x < NWPB) {
        int idx = blockIdx.x * 256 + threadIdx.x;
        int isbf = *flag;
        if (idx < NLAYER * 4 * 4 * 64 * 8) {
            int i    = idx & 7;
            int lane = (idx >> 3) & 63;
            int jt   = (idx >> 9) & 3;
            int s    = (idx >> 11) & 3;
            int l    = idx >> 13;
            int kfull = 32 * (s & 1) + 8 * (lane >> 4) + i;
            int col   = jt * 16 + (lane & 15);
            const void* W = (s < 2) ? W1 : W2;
            size_t off = (size_t)l * 4096 + (size_t)kfull * 64 + col;
            float v = isbf ? bf2f(((const ushort_t*)W)[off]) : ((const float*)W)[off];
            Wfrag[idx] = f2bf(v);
        } else {
            int r = idx - NLAYER * 4 * 4 * 64 * 8;
            if (r < NLAYER * 64) {
                float v1 = isbf ? bf2f(((const ushort_t*)b1)[r]) : ((const float*)b1)[r];
                float v2 = isbf ? bf2f(((const ushort_t*)b2)[r]) : ((const float*)b2)[r];
                bsum[r] = v1 + v2;
            }
        }
    } else {
        int t = threadIdx.x;
        if (t < NBKT) h[t] = 0;
        __syncthreads();
        int e0 = (blockIdx.x - NWPB) * 4096;
#pragma unroll
        for (int i = 0; i < 16; i++) {
            int e = e0 + t + i * 256;
            if (e < NNZC) atomicAdd(&h[rows[e] >> 10], 1);
        }
        __syncthreads();
        if (t < NBKT && h[t]) atomicAdd(&bucket_cnt[t], h[t]);
    }
}

// ---- exclusive scan of 147 bucket counts; seed bases/cursors ----
__global__ __launch_bounds__(256) void k_bscan(const int* __restrict__ bucket_cnt,
                                               int* __restrict__ gbase,
                                               int* __restrict__ gcursor) {
    __shared__ int s[256];
    int t = threadIdx.x;
    int v = (t < NBKT) ? bucket_cnt[t] : 0;
    s[t] = v; __syncthreads();
    for (int off = 1; off < 256; off <<= 1) {
        int x = (t >= off) ? s[t - off] : 0;
        __syncthreads();
        s[t] += x;
        __syncthreads();
    }
    if (t < NBKT) { int ex = s[t] - v; gbase[t] = ex; gcursor[t] = ex; }
    if (t == 0) { gbase[NBKT] = NNZC; }
}

// ---- phase A: partition edges into 147 row-buckets ----
__global__ __launch_bounds__(256) void k_phaseA(const int* __restrict__ rows,
                                                const int* __restrict__ cols,
                                                const void* __restrict__ vals,
                                                const int* __restrict__ flag,
                                                int* __restrict__ gcursor,
                                                int2* __restrict__ binned) {
    __shared__ int hist[NBKT], base_[NBKT], lcur[NBKT];
    int t = threadIdx.x;
    int e0 = blockIdx.x * 4096;
    if (t < NBKT) { hist[t] = 0; lcur[t] = 0; }
    __syncthreads();
    int myrow[16];
#pragma unroll
    for (int i = 0; i < 16; i++) {
        int e = e0 + t + i * 256;
        int r = -1;
        if (e < NNZC) { r = rows[e]; atomicAdd(&hist[r >> 10], 1); }
        myrow[i] = r;
    }
    __syncthreads();
    if (t < NBKT && hist[t] > 0) base_[t] = atomicAdd(&gcursor[t], hist[t]);
    __syncthreads();
    int isbf = *flag;
#pragma unroll
    for (int i = 0; i < 16; i++) {
        int e = e0 + t + i * 256;
        if (e < NNZC) {
            int r = myrow[i];
            int bkt = r >> 10;
            int off = atomicAdd(&lcur[bkt], 1);
            int pos = base_[bkt] + off;
            int c = cols[e];
            float v = isbf ? bf2f(((const ushort_t*)vals)[e]) : ((const float*)vals)[e];
            binned[pos] = make_int2(((r & 1023) << 18) | c, __float_as_int(v));
        }
    }
}

// ---- phase B (ELL): one block per bucket; per-row LDS cursors scatter edges
// into ell[row*32 + slot] (bucket-local 256KB window -> L2-resident writes);
// slot>=32 spills to overflow COO. Then zero-fill ONLY the dummy tails. ----
__global__ __launch_bounds__(256) void k_phaseB(const int* __restrict__ gbase,
                                                const int2* __restrict__ binned,
                                                int2* __restrict__ ell,
                                                int4* __restrict__ ovbuf,
                                                int* __restrict__ ovcnt) {
    __shared__ int rcur[1024];
    int b = blockIdx.x, t = threadIdx.x;
    int s = gbase[b], e = gbase[b + 1];
    for (int i = t; i < 1024; i += 256) rcur[i] = 0;
    __syncthreads();
    for (int i = s + t; i < e; i += 256) {
        int2 en = binned[i];
        int rl = en.x >> 18;
        int c  = en.x & 0x3FFFF;
        int off = atomicAdd(&rcur[rl], 1);
        if (off < ELLW) {
            ell[((size_t)(b * 1024 + rl)) * ELLW + off] = make_int2(c, en.y);
        } else {
            int p = atomicAdd(ovcnt, 1);
            if (p < OVCAP) ovbuf[p] = make_int4(b * 1024 + rl, c, en.y, 0);
        }
    }
    __syncthreads();
    // zero-fill dummy tails (rows with no edges, incl. rows >= NN, fill fully)
    for (int i = t; i < 1024; i += 256) {
        int start = rcur[i]; if (start > ELLW) start = ELLW;
        int2* rp = ell + ((size_t)(b * 1024 + i)) * ELLW;
        for (int j = start; j < ELLW; j++) rp[j] = make_int2(0, 0);
    }
}

static __device__ __forceinline__ int rid_to_node(int rid,
                                                  const int* users, const int* pos, const int* neg) {
    if (rid < BB)      return users[rid] - 1;
    if (rid < 2 * BB)  return N_USERC + pos[rid - BB] - 1;
    return N_USERC + neg[rid - 2 * BB] - 1;
}

// ---- k_initslice: blocks [0,NIB): Eb0 bf16 from inputs (bf16: lossless bit
// copy; fp32: round). Blocks [NIB,NISB): output slice 0 read directly from
// inputs. bf16-only state (verified rounds 7-9: absmax pinned at 2^-8 input
// quantization floor). ----
__global__ __launch_bounds__(256) void k_initslice(const void* __restrict__ ue,
                                                   const void* __restrict__ ie,
                                                   const int* __restrict__ flag,
                                                   ushort_t* __restrict__ Eb0,
                                                   const int* __restrict__ users,
                                                   const int* __restrict__ pos,
                                                   const int* __restrict__ neg,
                                                   float* __restrict__ out) {
    if (blockIdx.x < NIB) {
        int i4 = blockIdx.x * 256 + threadIdx.x;            // over NN*DD/4
        if (i4 >= NN * DD / 4) return;
        int idx = i4 * 4;
        int row = idx >> 6;
        bool isU = row < N_USERC;
        int si = isU ? idx : idx - N_USERC * DD;
        if (*flag) {
            const uint2* src = (const uint2*)((const ushort_t*)(isU ? ue : ie) + si);
            *(uint2*)(Eb0 + idx) = *src;                    // exact bit copy
        } else {
            const float* src = (const float*)(isU ? ue : ie) + si;
            ushort_t o[4];
#pragma unroll
            for (int k = 0; k < 4; k++) o[k] = f2bf(src[k]);
            *(uint2*)(Eb0 + idx) = *(uint2*)o;
        }
    } else {
        int rid  = (blockIdx.x - NIB) * 4 + (threadIdx.x >> 6);
        int lane = threadIdx.x & 63;
        if (rid >= NRID) return;
        int node = rid_to_node(rid, users, pos, neg);
        bool isU = node < N_USERC;
        int si = (isU ? node : node - N_USERC) * DD + lane;
        float v = (*flag) ? bf2f(isU ? ((const ushort_t*)ue)[si] : ((const ushort_t*)ie)[si])
                          : (isU ? ((const float*)ue)[si] : ((const float*)ie)[si]);
        out[(size_t)rid * 256 + lane] = v;
    }
}

// ---- fused layer v6 (ELL + 1-row-ahead pipeline + bf16-only state + fused
// prev-layer outnorm): blocks >= NTILE (launched only for layer>=1) compute
// the normalized output slice of the PREVIOUS layer from Eb_in (= prev ebo,
// complete at kernel entry) -> kills 2 outnorm launches; the work hides
// inside this latency-bound kernel. Blocks < NTILE unchanged from v5. ----
__global__ __launch_bounds__(256) void k_layer(const int2* __restrict__ ell,
                                               const int4* __restrict__ ovbuf,
                                               const int* __restrict__ ovcnt,
                                               const ushort_t* __restrict__ Eb_in,
                                               ushort_t* __restrict__ Eb_out,
                                               const ushort_t* __restrict__ Wfrag,
                                               const float* __restrict__ bsum,
                                               const int* __restrict__ users,
                                               const int* __restrict__ pos,
                                               const int* __restrict__ neg,
                                               float* __restrict__ out,
                                               int layer) {
    __shared__ float sLE[32][68];
    __shared__ float sE [32][68];

    int t    = threadIdx.x;
    int lane = t & 63;

    if (blockIdx.x >= NTILE) {
        // outnorm of previous layer's output (Eb_in), cbase = 64*layer
        int rid = (blockIdx.x - NTILE) * 4 + (t >> 6);
        if (rid < NRID) {
            int node = rid_to_node(rid, users, pos, neg);
            float v = bf2f(Eb_in[(size_t)node * DD + lane]);
            float p2 = v * v;
            for (int m = 1; m < 64; m <<= 1) p2 += __shfl_xor(p2, m, 64);
            float nr = fmaxf(sqrtf(p2), 1e-12f);
            out[(size_t)rid * 256 + 64 * layer + lane] = v / nr;
        }
        return;
    }

    int wv   = t >> 6;
    int oct  = lane >> 3;
    int d8   = (lane & 7) * 8;
    int hl   = lane >> 4;
    int l16  = lane & 15;
    int r0   = blockIdx.x << 5;

    // ---- sE staging: issue bf16 row loads now; LDS write deferred ----
    int lr_ = t >> 3;
    int dm_ = (t & 7) * 8;
    uint4 ev = make_uint4(0u, 0u, 0u, 0u);
    {
        int gr = r0 + lr_;
        if (gr < NN) ev = *(const uint4*)(Eb_in + (size_t)gr * DD + dm_);
    }

    // ---- phase 1: ELL spmm, 8 rows/wave, gather 1-row-ahead ----
    int baseRow = r0 + wv * 8;                       // max 150015 < ELLROWS
    int2 pv_c[4], pv_n[4];
    uint4 q_c[4];
#pragma unroll
    for (int v = 0; v < 4; v++)
        pv_c[v] = ell[(size_t)baseRow * ELLW + v * 8 + oct];
#pragma unroll
    for (int v = 0; v < 4; v++)
        q_c[v] = *(const uint4*)(Eb_in + ((size_t)(unsigned)pv_c[v].x << 6) + d8);
#pragma unroll
    for (int v = 0; v < 4; v++)
        pv_n[v] = ell[(size_t)(baseRow + 1) * ELLW + v * 8 + oct];

#pragma unroll
    for (int sub = 0; sub < 8; sub++) {
        uint4 q_n[4];
        int2 pv_n2[4];
        if (sub < 7) {
#pragma unroll
            for (int v = 0; v < 4; v++)
                q_n[v] = *(const uint4*)(Eb_in + ((size_t)(unsigned)pv_n[v].x << 6) + d8);
        }
        if (sub < 6) {
#pragma unroll
            for (int v = 0; v < 4; v++)
                pv_n2[v] = ell[(size_t)(baseRow + sub + 2) * ELLW + v * 8 + oct];
        }
        float acc[8];
#pragma unroll
        for (int k = 0; k < 8; k++) acc[k] = 0.f;
#pragma unroll
        for (int v = 0; v < 4; v++) {
            float w = __int_as_float(pv_c[v].y);
            acc[0] = fmaf(w, __uint_as_float(q_c[v].x << 16),         acc[0]);
            acc[1] = fmaf(w, __uint_as_float(q_c[v].x & 0xffff0000u), acc[1]);
            acc[2] = fmaf(w, __uint_as_float(q_c[v].y << 16),         acc[2]);
            acc[3] = fmaf(w, __uint_as_float(q_c[v].y & 0xffff0000u), acc[3]);
            acc[4] = fmaf(w, __uint_as_float(q_c[v].z << 16),         acc[4]);
            acc[5] = fmaf(w, __uint_as_float(q_c[v].z & 0xffff0000u), acc[5]);
            acc[6] = fmaf(w, __uint_as_float(q_c[v].w << 16),         acc[6]);
            acc[7] = fmaf(w, __uint_as_float(q_c[v].w & 0xffff0000u), acc[7]);
        }
#pragma unroll
        for (int m = 8; m < 64; m <<= 1)
#pragma unroll
            for (int k = 0; k < 8; k++) acc[k] += __shfl_xor(acc[k], m, 64);
        if (oct == 0) {
            int lr = wv * 8 + sub;
            *(float4*)&sLE[lr][d8]     = make_float4(acc[0], acc[1], acc[2], acc[3]);
            *(float4*)&sLE[lr][d8 + 4] = make_float4(acc[4], acc[5], acc[6], acc[7]);
        }
#pragma unroll
        for (int v = 0; v < 4; v++) {
            pv_c[v] = pv_n[v];
            q_c[v]  = q_n[v];
            pv_n[v] = pv_n2[v];
        }
    }

    // sE LDS write: unpack 8 bf16 -> f32 (loads landed long ago)
    sE[lr_][dm_ + 0] = __uint_as_float(ev.x << 16);
    sE[lr_][dm_ + 1] = __uint_as_float(ev.x & 0xffff0000u);
    sE[lr_][dm_ + 2] = __uint_as_float(ev.y << 16);
    sE[lr_][dm_ + 3] = __uint_as_float(ev.y & 0xffff0000u);
    sE[lr_][dm_ + 4] = __uint_as_float(ev.z << 16);
    sE[lr_][dm_ + 5] = __uint_as_float(ev.z & 0xffff0000u);
    sE[lr_][dm_ + 6] = __uint_as_float(ev.w << 16);
    sE[lr_][dm_ + 7] = __uint_as_float(ev.w & 0xffff0000u);
    __syncthreads();

    // ---- overflow COO: wave 0 scans the tiny list (expected ~40 entries) ----
    {
        int n = *ovcnt;
        n = (n < OVCAP) ? n : OVCAP;
        if (wv == 0) {
            for (int i = 0; i < n; i++) {
                int4 ov = ovbuf[i];
                if ((unsigned)(ov.x - r0) < 32u) {
                    float w = __int_as_float(ov.z);
                    sLE[ov.x - r0][lane] += w * bf2f(Eb_in[(size_t)ov.y * DD + lane]);
                }
            }
        }
    }
    __syncthreads();

    // ---- phase 2: dense MFMA. wave -> (rt = wv&1, jts = pair wv>>1) ----
    int rt = wv & 1;
    int j0w = wv >> 1;
    int jtA = 2 * j0w, jtB = 2 * j0w + 1;
    const uint4* wb = (const uint4*)(Wfrag + (size_t)layer * 8192);
    float bsA = bsum[layer * 64 + jtA * 16 + l16];
    float bsB = bsum[layer * 64 + jtB * 16 + l16];

    f32x4 accA = (f32x4){0.f, 0.f, 0.f, 0.f};
    f32x4 accB = (f32x4){0.f, 0.f, 0.f, 0.f};
    int lrow = rt * 16 + l16;

#pragma unroll
    for (int sh = 0; sh < 2; sh++) {
        bf16x8 w1a, w1b, w2a, w2b;
        {
            uint4 qa = wb[(sh * 4 + jtA) * 64 + lane];
            uint4 qb = wb[(sh * 4 + jtB) * 64 + lane];
            uint4 qc = wb[((2 + sh) * 4 + jtA) * 64 + lane];
            uint4 qd = wb[((2 + sh) * 4 + jtB) * 64 + lane];
            __builtin_memcpy(&w1a, &qa, 16);
            __builtin_memcpy(&w1b, &qb, 16);
            __builtin_memcpy(&w2a, &qc, 16);
            __builtin_memcpy(&w2b, &qd, 16);
        }
        const float* pl = &sLE[lrow][sh * 32 + hl * 8];
        const float* pe = &sE [lrow][sh * 32 + hl * 8];
        float4 l0 = *(const float4*)pl, l1 = *(const float4*)(pl + 4);
        float4 e0 = *(const float4*)pe, e1 = *(const float4*)(pe + 4);
        float le[8] = {l0.x, l0.y, l0.z, l0.w, l1.x, l1.y, l1.z, l1.w};
        float ee[8] = {e0.x, e0.y, e0.z, e0.w, e1.x, e1.y, e1.z, e1.w};
        unsigned int u1h[4], u1l[4], u2h[4], u2l[4];
#pragma unroll
        for (int d = 0; d < 4; d++) {
            float s0 = le[2*d]   + ee[2*d];
            float s1 = le[2*d+1] + ee[2*d+1];
            float m0 = le[2*d]   * ee[2*d];
            float m1 = le[2*d+1] * ee[2*d+1];
            asm("v_cvt_pk_bf16_f32 %0, %1, %2" : "=v"(u1h[d]) : "v"(s0), "v"(s1));
            asm("v_cvt_pk_bf16_f32 %0, %1, %2" : "=v"(u2h[d]) : "v"(m0), "v"(m1));
            float s0r = s0 - __uint_as_float(u1h[d] << 16);
            float s1r = s1 - __uint_as_float(u1h[d] & 0xffff0000u);
            float m0r = m0 - __uint_as_float(u2h[d] << 16);
            float m1r = m1 - __uint_as_float(u2h[d] & 0xffff0000u);
            asm("v_cvt_pk_bf16_f32 %0, %1, %2" : "=v"(u1l[d]) : "v"(s0r), "v"(s1r));
            asm("v_cvt_pk_bf16_f32 %0, %1, %2" : "=v"(u2l[d]) : "v"(m0r), "v"(m1r));
        }
        bf16x8 p1h, p1l, p2h, p2l;
        __builtin_memcpy(&p1h, u1h, 16);
        __builtin_memcpy(&p1l, u1l, 16);
        __builtin_memcpy(&p2h, u2h, 16);
        __builtin_memcpy(&p2l, u2l, 16);

        accA = __builtin_amdgcn_mfma_f32_16x16x32_bf16(p1h, w1a, accA, 0, 0, 0);
        accA = __builtin_amdgcn_mfma_f32_16x16x32_bf16(p1l, w1a, accA, 0, 0, 0);
        accA = __builtin_amdgcn_mfma_f32_16x16x32_bf16(p2h, w2a, accA, 0, 0, 0);
        accA = __builtin_amdgcn_mfma_f32_16x16x32_bf16(p2l, w2a, accA, 0, 0, 0);
        accB = __builtin_amdgcn_mfma_f32_16x16x32_bf16(p1h, w1b, accB, 0, 0, 0);
        accB = __builtin_amdgcn_mfma_f32_16x16x32_bf16(p1l, w1b, accB, 0, 0, 0);
        accB = __builtin_amdgcn_mfma_f32_16x16x32_bf16(p2h, w2b, accB, 0, 0, 0);
        accB = __builtin_amdgcn_mfma_f32_16x16x32_bf16(p2l, w2b, accB, 0, 0, 0);
    }

    // epilogue: bias + leaky relu -> Eb_out only (bf16 state)
#pragma unroll
    for (int g = 0; g < 4; g++) {
        int r = r0 + rt * 16 + hl * 4 + g;
        if (r < NN) {
            float hA = accA[g] + bsA; hA = (hA >= 0.f) ? hA : 0.2f * hA;
            float hB = accB[g] + bsB; hB = (hB >= 0.f) ? hB : 0.2f * hB;
            Eb_out[(size_t)r * DD + jtA * 16 + l16] = f2bf(hA);
            Eb_out[(size_t)r * DD + jtB * 16 + l16] = f2bf(hB);
        }
    }
}

// ---- final outnorm (layer NLAYER-1 output; earlier ones fused in k_layer) ----
__global__ __launch_bounds__(256) void k_outnorm(const ushort_t* __restrict__ Eb,
                                                 const int* __restrict__ users,
                                                 const int* __restrict__ pos,
                                                 const int* __restrict__ neg,
                                                 float* __restrict__ out,
                                                 int cbase) {
    int rid  = blockIdx.x * 4 + (threadIdx.x >> 6);
    int lane = threadIdx.x & 63;
    if (rid >= NRID) return;
    int node = rid_to_node(rid, users, pos, neg);
    float v = bf2f(Eb[(size_t)node * DD + lane]);
    float p2 = v * v;
    for (int m = 1; m < 64; m <<= 1) p2 += __shfl_xor(p2, m, 64);
    float nr = fmaxf(sqrtf(p2), 1e-12f);
    out[(size_t)rid * 256 + cbase + lane] = v / nr;
}

extern "C" void kernel_launch(void* const* d_in, const int* in_sizes, int n_in,
                              void* d_out, int out_size, void* d_ws, size_t ws_size,
                              hipStream_t stream) {
    const void* ue   = d_in[0];
    const void* ie   = d_in[1];
    const void* ev   = d_in[2];
    const void* W1   = d_in[3];
    const void* b1   = d_in[4];
    const void* W2   = d_in[5];
    const void* b2   = d_in[6];
    const int*  ei   = (const int*)d_in[7];
    const int*  usr  = (const int*)d_in[8];
    const int*  posi = (const int*)d_in[9];
    const int*  negi = (const int*)d_in[10];
    float*      out  = (float*)d_out;

    const int* rows = ei;
    const int* cols = ei + NNZC;

    // workspace carve — ~78 MB (Eb0 aliases binned: binned dead after phaseB)
    char* w = (char*)d_ws;
    ushort_t* Eb1     = (ushort_t*)w; w += (size_t)NN * DD * 2;      // 19.20 MB
    int2*   binned    = (int2*)w;   w += (size_t)NNZC * 8;           // 19.20 MB
    ushort_t* Eb0     = (ushort_t*)binned;                           // alias
    int2*   ell       = (int2*)w;   w += (size_t)ELLROWS * ELLW * 8; // 38.54 MB
    int4*   ovbuf     = (int4*)w;   w += (size_t)OVCAP * 16;         // 0.52 MB
    int*    ovcnt     = (int*)w;    w += 256;
    int*    gbase     = (int*)w;    w += 1024;
    int*    gcursor   = (int*)w;    w += 1024;
    int*    bucket_cnt= (int*)w;    w += 1024;
    int*    flag      = (int*)w;    w += 256;
    ushort_t* Wfrag   = (ushort_t*)w; w += 49152;                    // 3*4*4*64*8 bf16
    float*  bsum      = (float*)w;  w += 768;                        // 3*64 fp32

    k_sniffzb<<<1, 256, 0, stream>>>((const unsigned int*)ue, flag, bucket_cnt, ovcnt);
    k_prep<<<NPREPB, 256, 0, stream>>>(W1, W2, b1, b2, rows, flag, Wfrag, bsum, bucket_cnt);
    k_bscan<<<1, 256, 0, stream>>>(bucket_cnt, gbase, gcursor);
    k_phaseA<<<NABLK, 256, 0, stream>>>(rows, cols, ev, flag, gcursor, binned);
    k_phaseB<<<NBKT, 256, 0, stream>>>(gbase, binned, ell, ovbuf, ovcnt);
    k_initslice<<<NISB, 256, 0, stream>>>(ue, ie, flag, Eb0, usr, posi, negi, out);

    for (int l = 0; l < NLAYER; l++) {
        const ushort_t* ebi = (l & 1) ? Eb1 : Eb0;
        ushort_t*       ebo = (l & 1) ? Eb0 : Eb1;
        int grid = (l == 0) ? NTILE : (NTILE + NOSB);   // l>=1: + fused outnorm(l-1)
        k_layer<<<grid, 256, 0, stream>>>(ell, ovbuf, ovcnt, ebi, ebo, Wfrag, bsum,
                                          usr, posi, negi, out, l);
    }
    k_outnorm<<<3072, 256, 0, stream>>>(Eb1, usr, posi, negi, out, 64 * NLAYER);
}